// Round 7
// baseline (1977.071 us; speedup 1.0000x reference)
//
#include <hip/hip_runtime.h>
#include <hip/hip_bf16.h>
#include <stdint.h>

typedef __attribute__((ext_vector_type(8))) _Float16 half8;
typedef __attribute__((ext_vector_type(4))) float f32x4;
typedef __attribute__((ext_vector_type(4))) unsigned short us4;
typedef __attribute__((ext_vector_type(8))) unsigned short us8;
typedef __attribute__((ext_vector_type(4))) int i32x4;

#define N_TOK 8192
#define DIM   1024
#define HDIM  2048
#define ODIM  1024

__device__ __forceinline__ unsigned short f2h(float f) {
  _Float16 h = (_Float16)f;            // v_cvt_f16_f32, RNE
  union { _Float16 h; unsigned short u; } c; c.h = h; return c.u;
}

__device__ __forceinline__ void gload_lds16(const void* g, void* l) {
  __builtin_amdgcn_global_load_lds(
      (const __attribute__((address_space(1))) unsigned int*)g,
      (__attribute__((address_space(3))) unsigned int*)l, 16, 0, 0);
}

// ---------------------------------------------------------------------------
// fp16 GEMM over compacted (sparse-M) slot space — EXACT round-3-green 128x128
// structure (BK=32, 4 waves 2x2 of 64x64, double-buffered, 16 staging chunks),
// plus minimal sparse additions:
//   EPI=1: A rows gathered via lst; Hout[slot] = fp16(relu(C + bias[col]))
//   EPI=2: A rows = slots (Hh contiguous); Y[lst[slot]] += Wg[lst[slot]*8+e]*C
//          guarded by slot < cntTrue[e] (pad-duplicate slots never store).
// Blocks with rowbase >= cntPad[e] exit uniformly before any barrier.
// ---------------------------------------------------------------------------
template <int EPI>
__global__ __launch_bounds__(256) void gemm_kernel(
    const unsigned short* __restrict__ A, const unsigned short* __restrict__ B,
    int N, int K,
    const float* __restrict__ bias, unsigned short* __restrict__ Hout,
    const float* __restrict__ Wg, int e, float* __restrict__ Y,
    const int* __restrict__ lst, const int* __restrict__ cntTrue,
    const int* __restrict__ cntPad)
{
  __shared__ half8 ldsA[2][512];
  __shared__ half8 ldsB[2][512];
  const int lane = threadIdx.x & 63, wid = threadIdx.x >> 6;
  const int wr = wid >> 1, wc = wid & 1;

  // T1: XCD swizzle. nwg = gridDim.x*gridDim.y is a multiple of 8.
  const int nwg = gridDim.x * gridDim.y;
  const int orig = blockIdx.y * gridDim.x + blockIdx.x;
  const int qq = nwg >> 3;
  const int swz = (orig & 7) * qq + (orig >> 3);
  const int bx = swz % gridDim.x, by = swz / gridDim.x;
  const int rowbase = by * 128, colbase = bx * 128;

  const int padc = cntPad[e];
  if (rowbase >= padc) return;          // uniform per block, before any barrier

  // gathered A rows (EPI=1 only); EPI=2 uses slot index directly
  int rG0 = rowbase + lane, rG1 = rowbase + 64 + lane;
  if (EPI == 1) { rG0 = lst[rG0]; rG1 = lst[rG1]; }

  f32x4 acc[4][4];
#pragma unroll
  for (int m = 0; m < 4; ++m)
#pragma unroll
    for (int n = 0; n < 4; ++n) acc[m][n] = f32x4{0.f, 0.f, 0.f, 0.f};

  auto stage = [&](int buf, int ktile) {
#pragma unroll
    for (int i = 0; i < 4; ++i) {
      const int c = wid * 4 + i;           // 16 chunks: 8 A + 8 B, each 1KB
      const int cc = c & 7, kq = cc >> 1, half = cc & 1;
      const int koff = ktile * 32 + kq * 8;
      if (c < 8) {
        const int arow = half ? rG1 : rG0;
        gload_lds16(A + (size_t)arow * K + koff,
                    &ldsA[buf][kq * 128 + half * 64]);
      } else {
        gload_lds16(B + (size_t)(colbase + half * 64 + lane) * K + koff,
                    &ldsB[buf][kq * 128 + half * 64]);
      }
    }
  };

  const int KT = K >> 5;
  stage(0, 0);
  for (int kt = 0; kt < KT; ++kt) {
    const int buf = kt & 1;
    __syncthreads();                      // drains vmcnt+lgkmcnt for buf
    if (kt + 1 < KT) stage(buf ^ 1, kt + 1);

    half8 af[4], bfr[4];
    const int kqo = (lane >> 4) * 128;
    const int rA = wr * 64 + (lane & 15);
    const int rB = wc * 64 + (lane & 15);
#pragma unroll
    for (int m = 0; m < 4; ++m) af[m] = ldsA[buf][kqo + rA + m * 16];
#pragma unroll
    for (int n = 0; n < 4; ++n) bfr[n] = ldsB[buf][kqo + rB + n * 16];
#pragma unroll
    for (int m = 0; m < 4; ++m)
#pragma unroll
      for (int n = 0; n < 4; ++n)
        acc[m][n] = __builtin_amdgcn_mfma_f32_16x16x32_f16(af[m], bfr[n], acc[m][n], 0, 0, 0);
  }

  const int r0 = rowbase + wr * 64, c0 = colbase + wc * 64;
  if (EPI == 1) {
#pragma unroll
    for (int n = 0; n < 4; ++n) {
      const int col = c0 + n * 16 + (lane & 15);
      const float bv = bias[col];
#pragma unroll
      for (int m = 0; m < 4; ++m)
#pragma unroll
        for (int r = 0; r < 4; ++r) {
          const int slot = r0 + m * 16 + (lane >> 4) * 4 + r;
          float v = acc[m][n][r] + bv;
          v = v > 0.f ? v : 0.f;
          Hout[(size_t)slot * N + col] = f2h(v);
        }
    }
  } else {
    const int cntT = cntTrue[e];
#pragma unroll
    for (int m = 0; m < 4; ++m) {
      const int sbase = r0 + m * 16 + (lane >> 4) * 4;
      const i32x4 og = *(const i32x4*)&lst[sbase];
#pragma unroll
      for (int r = 0; r < 4; ++r) {
        const int slot = sbase + r;
        if (slot < cntT) {
          const int otok = og[r];
          const float wv = Wg[otok * 8 + e];
#pragma unroll
          for (int n = 0; n < 4; ++n) {
            const int col = c0 + n * 16 + (lane & 15);
            Y[(size_t)otok * ODIM + col] += wv * acc[m][n][r];
          }
        }
      }
    }
  }
}

// ---------------------------------------------------------------------------
// Gating v1 (round-3 GREEN verbatim): one wave per token, fp32 throughout.
// Also emits the fp16 cast of x (fused — x is already streaming through).
// ---------------------------------------------------------------------------
__global__ __launch_bounds__(256) void gating_kernel(
    const float* __restrict__ x,
    const float* __restrict__ gate_w, const float* __restrict__ gate_b,
    const float* __restrict__ ph_w1, const float* __restrict__ ph_b1,
    const float* __restrict__ ph_w2, const float* __restrict__ ph_b2,
    const float* __restrict__ cl_w1, const float* __restrict__ cl_b1,
    const float* __restrict__ cl_w2, const float* __restrict__ cl_b2,
    const float* __restrict__ sigs,
    unsigned short* __restrict__ xh,
    float* __restrict__ eff_o,
    float* __restrict__ pclar, float* __restrict__ pP)
{
  const int lane = threadIdx.x & 63, wid = threadIdx.x >> 6;
  const int tok = blockIdx.x * 4 + wid;

  float g[8], p1[32], c1[16];
#pragma unroll
  for (int i = 0; i < 8; ++i) g[i] = 0.f;
#pragma unroll
  for (int i = 0; i < 32; ++i) p1[i] = 0.f;
#pragma unroll
  for (int i = 0; i < 16; ++i) c1[i] = 0.f;

  const f32x4* x4 = (const f32x4*)(x + (size_t)tok * DIM);
  us4* xh4 = (us4*)(xh + (size_t)tok * DIM);
#pragma unroll
  for (int d0 = 0; d0 < 4; ++d0) {
    const f32x4 xv = x4[d0 * 64 + lane];
    us4 ov;
#pragma unroll
    for (int j = 0; j < 4; ++j) {
      const int d = (d0 * 64 + lane) * 4 + j;
      const float xd = xv[j];
      ov[j] = f2h(xd);
      const f32x4* gw = (const f32x4*)(gate_w + d * 8);
#pragma unroll
      for (int q = 0; q < 2; ++q) { const f32x4 w = gw[q];
#pragma unroll
        for (int r = 0; r < 4; ++r) g[q * 4 + r] += xd * w[r]; }
      const f32x4* pw = (const f32x4*)(ph_w1 + d * 32);
#pragma unroll
      for (int q = 0; q < 8; ++q) { const f32x4 w = pw[q];
#pragma unroll
        for (int r = 0; r < 4; ++r) p1[q * 4 + r] += xd * w[r]; }
      const f32x4* cw = (const f32x4*)(cl_w1 + d * 16);
#pragma unroll
      for (int q = 0; q < 4; ++q) { const f32x4 w = cw[q];
#pragma unroll
        for (int r = 0; r < 4; ++r) c1[q * 4 + r] += xd * w[r]; }
    }
    xh4[d0 * 64 + lane] = ov;
  }
  // wave64 butterfly reductions
#pragma unroll
  for (int i = 0; i < 8; ++i)
#pragma unroll
    for (int s = 0; s < 6; ++s) g[i] += __shfl_xor(g[i], 1 << s);
#pragma unroll
  for (int i = 0; i < 32; ++i)
#pragma unroll
    for (int s = 0; s < 6; ++s) p1[i] += __shfl_xor(p1[i], 1 << s);
#pragma unroll
  for (int i = 0; i < 16; ++i)
#pragma unroll
    for (int s = 0; s < 6; ++s) c1[i] += __shfl_xor(c1[i], 1 << s);

  // softmax((scores+b)/e)
  float sc[8]; float mx = -1e30f;
#pragma unroll
  for (int k = 0; k < 8; ++k) { sc[k] = (g[k] + gate_b[k]) / 2.718281828459045f; mx = fmaxf(mx, sc[k]); }
  float ex[8]; float sum = 0.f;
#pragma unroll
  for (int k = 0; k < 8; ++k) { ex[k] = expf(sc[k] - mx); sum += ex[k]; }
  float pe[8];
#pragma unroll
  for (int k = 0; k < 8; ++k) pe[k] = ex[k] / sum;

  // ph feature -> normalize -> match
  float rh[32];
#pragma unroll
  for (int h = 0; h < 32; ++h) { const float v = p1[h] + ph_b1[h]; rh[h] = v > 0.f ? v : 0.f; }
  float feat[16];
#pragma unroll
  for (int q = 0; q < 16; ++q) {
    float f = ph_b2[q];
#pragma unroll
    for (int h = 0; h < 32; ++h) f += rh[h] * ph_w2[h * 16 + q];
    feat[q] = f;
  }
  float nn = 0.f;
#pragma unroll
  for (int q = 0; q < 16; ++q) nn += feat[q] * feat[q];
  const float den = fmaxf(sqrtf(nn), 1e-12f);
#pragma unroll
  for (int q = 0; q < 16; ++q) feat[q] = feat[q] / den;

  float eff[8];
#pragma unroll
  for (int k = 0; k < 8; ++k) {
    float s2 = 0.f;
#pragma unroll
    for (int q = 0; q < 16; ++q) { const float sv = sigs[k * 16 + q]; s2 += sv * sv; }
    const float sden = fmaxf(sqrtf(s2), 1e-12f);
    float dot = 0.f;
#pragma unroll
    for (int q = 0; q < 16; ++q) dot += feat[q] * (sigs[k * 16 + q] / sden);
    eff[k] = pe[k] * ((dot + 1.0f) / 2.0f);
  }

  // clarity
  float z = cl_b2[0];
#pragma unroll
  for (int c = 0; c < 16; ++c) { float v = c1[c] + cl_b1[c]; v = v > 0.f ? v : 0.f; z += v * cl_w2[c]; }
  const float clar = 1.0f / (1.0f + expf(-z));

  if (lane == 0) {
#pragma unroll
    for (int k = 0; k < 8; ++k) eff_o[tok * 8 + k] = eff[k];
  }
  __shared__ float shc[4];
  __shared__ float shP[4][8];
  if (lane == 0) { shc[wid] = clar;
#pragma unroll
    for (int k = 0; k < 8; ++k) shP[wid][k] = pe[k]; }
  __syncthreads();
  if (threadIdx.x == 0) {
    pclar[blockIdx.x] = shc[0] + shc[1] + shc[2] + shc[3];
#pragma unroll
    for (int k = 0; k < 8; ++k)
      pP[blockIdx.x * 8 + k] = shP[0][k] + shP[1][k] + shP[2][k] + shP[3][k];
  }
}

// ---------------------------------------------------------------------------
__global__ void zero_kernel(int* __restrict__ gcount) {
  if (threadIdx.x < 8) gcount[threadIdx.x] = 0;
}

// k + top-k mask + weight normalization + active counts + per-expert lists
__global__ __launch_bounds__(256) void weights_kernel(
    const float* __restrict__ eff_i, const float* __restrict__ pclar,
    float* __restrict__ wout, int* __restrict__ f_part,
    int* __restrict__ gcount, int* __restrict__ lst)
{
  __shared__ float red[256];
  __shared__ int cnt[8];
  __shared__ int ksh;
  const int tid = threadIdx.x;
  float s = 0.f;
  for (int i = tid; i < 2048; i += 256) s += pclar[i];
  red[tid] = s; __syncthreads();
  for (int off = 128; off > 0; off >>= 1) { if (tid < off) red[tid] += red[tid + off]; __syncthreads(); }
  if (tid == 0) {
    const float mean_na = 8.0f - 6.0f * (red[0] / 8192.0f);
    int k = (int)floorf(mean_na + 0.5f);
    ksh = k < 2 ? 2 : (k > 8 ? 8 : k);
  }
  if (tid < 8) cnt[tid] = 0;
  __syncthreads();
  const int k = ksh;
  const int t = blockIdx.x * 256 + tid;
  const f32x4* ep = (const f32x4*)(eff_i + t * 8);
  const f32x4 ea = ep[0], eb = ep[1];
  const float ef[8] = {ea[0], ea[1], ea[2], ea[3], eb[0], eb[1], eb[2], eb[3]};
  float w[8]; float wsum = 0.f; int act[8];
#pragma unroll
  for (int e2 = 0; e2 < 8; ++e2) {
    int r = 0;
#pragma unroll
    for (int j = 0; j < 8; ++j) r += (int)((ef[j] > ef[e2]) || ((j < e2) && (ef[j] == ef[e2])));
    const float we = (r < k) ? ef[e2] : 0.f;
    w[e2] = we; wsum += we; act[e2] = we > 0.f ? 1 : 0;
  }
  const float dn = wsum + 1e-8f;
#pragma unroll
  for (int e2 = 0; e2 < 8; ++e2) wout[t * 8 + e2] = w[e2] / dn;
#pragma unroll
  for (int e2 = 0; e2 < 8; ++e2)
    if (act[e2]) {
      atomicAdd(&cnt[e2], 1);
      const int p = atomicAdd(&gcount[e2], 1);
      lst[e2 * N_TOK + p] = t;
    }
  __syncthreads();
  if (tid < 8) f_part[blockIdx.x * 8 + tid] = cnt[tid];
}

// pad each expert list to a multiple of 128 with a duplicate token
__global__ __launch_bounds__(256) void pad_kernel(
    const int* __restrict__ gcount, int* __restrict__ gpad, int* __restrict__ lst)
{
  const int tid = threadIdx.x;
  for (int e2 = 0; e2 < 8; ++e2) {
    const int a = gcount[e2];
    const int pc = (a + 127) & ~127;
    if (tid == 0) gpad[e2] = pc;
    if (a > 0) {
      const int last = lst[e2 * N_TOK + a - 1];
      for (int i = a + tid; i < pc; i += 256) lst[e2 * N_TOK + i] = last;
    }
  }
}

__global__ __launch_bounds__(256) void lb_kernel(
    const float* __restrict__ pP, const int* __restrict__ f_part, float* __restrict__ lbout)
{
  __shared__ float red[256];
  __shared__ float Ps[8], Fs[8];
  const int tid = threadIdx.x;
  for (int e2 = 0; e2 < 8; ++e2) {
    float s = 0.f;
    for (int i = tid; i < 2048; i += 256) s += pP[i * 8 + e2];
    red[tid] = s; __syncthreads();
    for (int off = 128; off > 0; off >>= 1) { if (tid < off) red[tid] += red[tid + off]; __syncthreads(); }
    if (tid == 0) Ps[e2] = red[0];
    __syncthreads();
    red[tid] = (tid < 32) ? (float)f_part[tid * 8 + e2] : 0.f;
    __syncthreads();
    for (int off = 128; off > 0; off >>= 1) { if (tid < off) red[tid] += red[tid + off]; __syncthreads(); }
    if (tid == 0) Fs[e2] = red[0];
    __syncthreads();
  }
  if (tid == 0) {
    float lb = 0.f;
    for (int e2 = 0; e2 < 8; ++e2) lb += (Fs[e2] / 8192.0f) * (Ps[e2] / 8192.0f);
    lbout[0] = 0.01f * 8.0f * lb;
  }
}

__global__ __launch_bounds__(256) void yinit_kernel(
    const float* __restrict__ w, const float* __restrict__ b2, float* __restrict__ y)
{
  const int idx = blockIdx.x * 256 + threadIdx.x;   // over N*O/4
  const int n = idx >> 8, o4 = idx & 255;
  const f32x4* bv = (const f32x4*)b2;
  f32x4 a = f32x4{0.f, 0.f, 0.f, 0.f};
  const float* wr = w + n * 8;
#pragma unroll
  for (int e2 = 0; e2 < 8; ++e2) a += wr[e2] * bv[e2 * 256 + o4];
  ((f32x4*)y)[idx] = a;
}

// per-expert [R,C] f32 -> [C,R] fp16
__global__ __launch_bounds__(256) void transpose_kernel(
    const float* __restrict__ in, unsigned short* __restrict__ out, int R, int C)
{
  __shared__ __align__(16) unsigned short tb[64][72];
  const float* ip = in + (size_t)blockIdx.z * R * C;
  unsigned short* op = out + (size_t)blockIdx.z * R * C;
  const int r0 = blockIdx.y * 64, c0 = blockIdx.x * 64;
  const int tr = threadIdx.x >> 4, tc4 = (threadIdx.x & 15) * 4;
#pragma unroll
  for (int i = 0; i < 4; ++i) {
    const int rr = tr + i * 16;
    const f32x4 v = *(const f32x4*)(ip + (size_t)(r0 + rr) * C + c0 + tc4);
#pragma unroll
    for (int j = 0; j < 4; ++j) tb[tc4 + j][rr] = f2h(v[j]);
  }
  __syncthreads();
  const int oc = threadIdx.x >> 3, or8 = (threadIdx.x & 7) * 8;
#pragma unroll
  for (int i = 0; i < 2; ++i) {
    const int c = oc + i * 32;
    const us8 v = *(const us8*)&tb[c][or8];
    *(us8*)(op + (size_t)(c0 + c) * R + r0 + or8) = v;
  }
}

// ---------------------------------------------------------------------------
extern "C" void kernel_launch(void* const* d_in, const int* in_sizes, int n_in,
                              void* d_out, int out_size, void* d_ws, size_t ws_size,
                              hipStream_t stream)
{
  const float* x      = (const float*)d_in[0];
  const float* gate_w = (const float*)d_in[1];
  const float* gate_b = (const float*)d_in[2];
  const float* ph_w1  = (const float*)d_in[3];
  const float* ph_b1  = (const float*)d_in[4];
  const float* ph_w2  = (const float*)d_in[5];
  const float* ph_b2  = (const float*)d_in[6];
  const float* cl_w1  = (const float*)d_in[7];
  const float* cl_b1  = (const float*)d_in[8];
  const float* cl_w2  = (const float*)d_in[9];
  const float* cl_b2  = (const float*)d_in[10];
  const float* sigs   = (const float*)d_in[11];
  const float* e_w1   = (const float*)d_in[12];
  const float* e_b1   = (const float*)d_in[13];
  const float* e_w2   = (const float*)d_in[14];
  const float* e_b2   = (const float*)d_in[15];
  float* y = (float*)d_out;
  char* ws = (char*)d_ws;

  float* eff    = (float*)(ws + 0);          // 8192*8*4
  float* wts    = (float*)(ws + 262144);     // 8192*8*4
  float* pclar  = (float*)(ws + 524288);     // 2048*4
  float* pP     = (float*)(ws + 532480);     // 2048*8*4
  int*   f_part = (int*)(ws + 598016);       // 32*8*4
  int*   gcount = (int*)(ws + 599040);       // 8*4
  int*   gpad   = (int*)(ws + 599072);       // 8*4
  int*   lst    = (int*)(ws + 655360);       // 8*8192*4
  unsigned short* xh  = (unsigned short*)(ws + 1048576);     // [N][D] fp16
  unsigned short* W1T = (unsigned short*)(ws + 17825792u);   // [E][H][D] fp16
  unsigned short* W2T = (unsigned short*)(ws + 51380224u);   // [E][O][H] fp16
  unsigned short* Hh  = (unsigned short*)(ws + 84934656u);   // [slots][H] fp16

  transpose_kernel<<<dim3(32, 16, 8), 256, 0, stream>>>(e_w1, W1T, 1024, 2048);
  transpose_kernel<<<dim3(16, 32, 8), 256, 0, stream>>>(e_w2, W2T, 2048, 1024);
  gating_kernel<<<2048, 256, 0, stream>>>(x, gate_w, gate_b, ph_w1, ph_b1, ph_w2, ph_b2,
                                          cl_w1, cl_b1, cl_w2, cl_b2, sigs,
                                          xh, eff, pclar, pP);
  zero_kernel<<<1, 64, 0, stream>>>(gcount);
  weights_kernel<<<32, 256, 0, stream>>>(eff, pclar, wts, f_part, gcount, lst);
  pad_kernel<<<1, 256, 0, stream>>>(gcount, gpad, lst);
  lb_kernel<<<1, 256, 0, stream>>>(pP, f_part, y + (size_t)N_TOK * ODIM);
  yinit_kernel<<<8192, 256, 0, stream>>>(wts, e_b2, y);

  for (int e2 = 0; e2 < 8; ++e2) {
    gemm_kernel<1><<<dim3(16, 64), 256, 0, stream>>>(
        xh, W1T + (size_t)e2 * HDIM * DIM, HDIM, DIM,
        e_b1 + e2 * HDIM, Hh, nullptr, e2, nullptr,
        lst + (size_t)e2 * N_TOK, gcount, gpad);
    gemm_kernel<2><<<dim3(8, 64), 256, 0, stream>>>(
        Hh, W2T + (size_t)e2 * ODIM * HDIM, ODIM, HDIM,
        nullptr, nullptr, wts, e2, y,
        lst + (size_t)e2 * N_TOK, gcount, gpad);
  }
}

// Round 9
// 1891.885 us; speedup vs baseline: 1.0450x; 1.0450x over previous
//
#include <hip/hip_runtime.h>
#include <hip/hip_bf16.h>
#include <stdint.h>

typedef __attribute__((ext_vector_type(8))) _Float16 half8;
typedef __attribute__((ext_vector_type(4))) float f32x4;
typedef __attribute__((ext_vector_type(4))) unsigned short us4;
typedef __attribute__((ext_vector_type(8))) unsigned short us8;
typedef __attribute__((ext_vector_type(4))) int i32x4;

#define N_TOK 8192
#define DIM   1024
#define HDIM  2048
#define ODIM  1024

__device__ __forceinline__ unsigned short f2h(float f) {
  _Float16 h = (_Float16)f;            // v_cvt_f16_f32, RNE
  union { _Float16 h; unsigned short u; } c; c.h = h; return c.u;
}

__device__ __forceinline__ void gload_lds16(const void* g, void* l) {
  __builtin_amdgcn_global_load_lds(
      (const __attribute__((address_space(1))) unsigned int*)g,
      (__attribute__((address_space(3))) unsigned int*)l, 16, 0, 0);
}

// ---------------------------------------------------------------------------
// fp16 GEMM over compacted (sparse-M) slot space — round-7 GREEN verbatim.
// 128x128, BK=32, 4 waves 2x2 of 64x64, double-buffered, global_load_lds.
//   EPI=1: A rows gathered via lst; Hout[slot] = fp16(relu(C + bias[col]))
//   EPI=2: A rows = slots (Hh contiguous); Y[lst[slot]] += Wg[lst[slot]*8+e]*C
//          guarded by slot < cntTrue[e] (pad-duplicate slots never store).
// Blocks with rowbase >= cntPad[e] exit uniformly before any barrier.
// ---------------------------------------------------------------------------
template <int EPI>
__global__ __launch_bounds__(256) void gemm_kernel(
    const unsigned short* __restrict__ A, const unsigned short* __restrict__ B,
    int N, int K,
    const float* __restrict__ bias, unsigned short* __restrict__ Hout,
    const float* __restrict__ Wg, int e, float* __restrict__ Y,
    const int* __restrict__ lst, const int* __restrict__ cntTrue,
    const int* __restrict__ cntPad)
{
  __shared__ half8 ldsA[2][512];
  __shared__ half8 ldsB[2][512];
  const int lane = threadIdx.x & 63, wid = threadIdx.x >> 6;
  const int wr = wid >> 1, wc = wid & 1;

  // T1: XCD swizzle. nwg = gridDim.x*gridDim.y is a multiple of 8.
  const int nwg = gridDim.x * gridDim.y;
  const int orig = blockIdx.y * gridDim.x + blockIdx.x;
  const int qq = nwg >> 3;
  const int swz = (orig & 7) * qq + (orig >> 3);
  const int bx = swz % gridDim.x, by = swz / gridDim.x;
  const int rowbase = by * 128, colbase = bx * 128;

  const int padc = cntPad[e];
  if (rowbase >= padc) return;          // uniform per block, before any barrier

  // gathered A rows (EPI=1 only); EPI=2 uses slot index directly
  int rG0 = rowbase + lane, rG1 = rowbase + 64 + lane;
  if (EPI == 1) { rG0 = lst[rG0]; rG1 = lst[rG1]; }

  f32x4 acc[4][4];
#pragma unroll
  for (int m = 0; m < 4; ++m)
#pragma unroll
    for (int n = 0; n < 4; ++n) acc[m][n] = f32x4{0.f, 0.f, 0.f, 0.f};

  auto stage = [&](int buf, int ktile) {
#pragma unroll
    for (int i = 0; i < 4; ++i) {
      const int c = wid * 4 + i;           // 16 chunks: 8 A + 8 B, each 1KB
      const int cc = c & 7, kq = cc >> 1, half = cc & 1;
      const int koff = ktile * 32 + kq * 8;
      if (c < 8) {
        const int arow = half ? rG1 : rG0;
        gload_lds16(A + (size_t)arow * K + koff,
                    &ldsA[buf][kq * 128 + half * 64]);
      } else {
        gload_lds16(B + (size_t)(colbase + half * 64 + lane) * K + koff,
                    &ldsB[buf][kq * 128 + half * 64]);
      }
    }
  };

  const int KT = K >> 5;
  stage(0, 0);
  for (int kt = 0; kt < KT; ++kt) {
    const int buf = kt & 1;
    __syncthreads();                      // drains vmcnt+lgkmcnt for buf
    if (kt + 1 < KT) stage(buf ^ 1, kt + 1);

    half8 af[4], bfr[4];
    const int kqo = (lane >> 4) * 128;
    const int rA = wr * 64 + (lane & 15);
    const int rB = wc * 64 + (lane & 15);
#pragma unroll
    for (int m = 0; m < 4; ++m) af[m] = ldsA[buf][kqo + rA + m * 16];
#pragma unroll
    for (int n = 0; n < 4; ++n) bfr[n] = ldsB[buf][kqo + rB + n * 16];
#pragma unroll
    for (int m = 0; m < 4; ++m)
#pragma unroll
      for (int n = 0; n < 4; ++n)
        acc[m][n] = __builtin_amdgcn_mfma_f32_16x16x32_f16(af[m], bfr[n], acc[m][n], 0, 0, 0);
  }

  const int r0 = rowbase + wr * 64, c0 = colbase + wc * 64;
  if (EPI == 1) {
#pragma unroll
    for (int n = 0; n < 4; ++n) {
      const int col = c0 + n * 16 + (lane & 15);
      const float bv = bias[col];
#pragma unroll
      for (int m = 0; m < 4; ++m)
#pragma unroll
        for (int r = 0; r < 4; ++r) {
          const int slot = r0 + m * 16 + (lane >> 4) * 4 + r;
          float v = acc[m][n][r] + bv;
          v = v > 0.f ? v : 0.f;
          Hout[(size_t)slot * N + col] = f2h(v);
        }
    }
  } else {
    const int cntT = cntTrue[e];
#pragma unroll
    for (int m = 0; m < 4; ++m) {
      const int sbase = r0 + m * 16 + (lane >> 4) * 4;
      const i32x4 og = *(const i32x4*)&lst[sbase];
#pragma unroll
      for (int r = 0; r < 4; ++r) {
        const int slot = sbase + r;
        if (slot < cntT) {
          const int otok = og[r];
          const float wv = Wg[otok * 8 + e];
#pragma unroll
          for (int n = 0; n < 4; ++n) {
            const int col = c0 + n * 16 + (lane & 15);
            Y[(size_t)otok * ODIM + col] += wv * acc[m][n][r];
          }
        }
      }
    }
  }
}

// ---------------------------------------------------------------------------
// Gating v3: weights + x staged in LDS; lane = output column; NO shfl.
// Block = 256 threads = 4 token-waves. Wcat[1024][56] (gate|ph_w1|cl_w1)
// staged in 8 chunks of 128 rows (Wl 30.7 KB, total static LDS ~34 KB < 64).
// Lane o (o = lane<56 ? lane : lane-56) accumulates S[tok][o]; x values are
// read back from xs[] at wave-uniform addresses (LDS broadcast). Tail math
// is identical to the twice-green v1. Also emits the fp16 cast of x.
// ---------------------------------------------------------------------------
__global__ __launch_bounds__(256) void gating_kernel(
    const float* __restrict__ x,
    const float* __restrict__ gate_w, const float* __restrict__ gate_b,
    const float* __restrict__ ph_w1, const float* __restrict__ ph_b1,
    const float* __restrict__ ph_w2, const float* __restrict__ ph_b2,
    const float* __restrict__ cl_w1, const float* __restrict__ cl_b1,
    const float* __restrict__ cl_w2, const float* __restrict__ cl_b2,
    const float* __restrict__ sigs,
    unsigned short* __restrict__ xh,
    float* __restrict__ eff_o,
    float* __restrict__ pclar, float* __restrict__ pP)
{
  __shared__ float Wl[128][60];          // 60-stride: rows 16B-aligned
  __shared__ float xs[4][128];
  __shared__ float sS[4][56];
  __shared__ float shc[4];
  __shared__ float shP[4][8];

  const int t = threadIdx.x;
  const int lane = t & 63, wid = t >> 6;
  const int tok = blockIdx.x * 4 + wid;
  const int o = lane < 56 ? lane : lane - 56;

  const f32x4* x4 = (const f32x4*)(x + (size_t)tok * DIM);
  us4* xh4 = (us4*)(xh + (size_t)tok * DIM);

  float acc = 0.f;

#pragma unroll 1
  for (int c = 0; c < 8; ++c) {
    __syncthreads();                     // previous chunk's reads done
    if (t < 128) {                       // stage Wcat rows [c*128, c*128+128)
      const int gr = c * 128 + t;
      const float* grow = gate_w + (size_t)gr * 8;
      *(f32x4*)&Wl[t][0] = *(const f32x4*)(grow);
      *(f32x4*)&Wl[t][4] = *(const f32x4*)(grow + 4);
      const float* prow = ph_w1 + (size_t)gr * 32;
#pragma unroll
      for (int q = 0; q < 8; ++q)
        *(f32x4*)&Wl[t][8 + 4 * q] = *(const f32x4*)(prow + 4 * q);
      const float* crow = cl_w1 + (size_t)gr * 16;
#pragma unroll
      for (int q = 0; q < 4; ++q)
        *(f32x4*)&Wl[t][40 + 4 * q] = *(const f32x4*)(crow + 4 * q);
    }
    if (lane < 32) {                     // stage this wave's x chunk + cast
      const int l32 = lane;
      const f32x4 xv = x4[c * 32 + l32];
      us4 ov;
#pragma unroll
      for (int j = 0; j < 4; ++j) ov[j] = f2h(xv[j]);
      xh4[c * 32 + l32] = ov;
      *(f32x4*)&xs[wid][l32 * 4] = xv;
    }
    __syncthreads();

#pragma unroll
    for (int i4 = 0; i4 < 32; ++i4) {
      const f32x4 xq = *(const f32x4*)&xs[wid][i4 * 4];  // LDS broadcast
      acc += xq[0] * Wl[i4 * 4 + 0][o];
      acc += xq[1] * Wl[i4 * 4 + 1][o];
      acc += xq[2] * Wl[i4 * 4 + 2][o];
      acc += xq[3] * Wl[i4 * 4 + 3][o];
    }
  }

  if (lane < 56) sS[wid][lane] = acc;
  __syncthreads();

  // tail (redundant per lane) — identical math to twice-green v1
  float S[56];
#pragma unroll
  for (int q = 0; q < 56; ++q) S[q] = sS[wid][q];

  float sc[8]; float mx = -1e30f;
#pragma unroll
  for (int k = 0; k < 8; ++k) { sc[k] = (S[k] + gate_b[k]) / 2.718281828459045f; mx = fmaxf(mx, sc[k]); }
  float sum = 0.f; float pe[8];
#pragma unroll
  for (int k = 0; k < 8; ++k) { pe[k] = expf(sc[k] - mx); sum += pe[k]; }
#pragma unroll
  for (int k = 0; k < 8; ++k) pe[k] /= sum;

  float rh[32];
#pragma unroll
  for (int h = 0; h < 32; ++h) { const float v = S[8 + h] + ph_b1[h]; rh[h] = v > 0.f ? v : 0.f; }
  float feat[16];
#pragma unroll
  for (int q = 0; q < 16; ++q) {
    float f = ph_b2[q];
#pragma unroll
    for (int h = 0; h < 32; ++h) f += rh[h] * ph_w2[h * 16 + q];
    feat[q] = f;
  }
  float nn = 0.f;
#pragma unroll
  for (int q = 0; q < 16; ++q) nn += feat[q] * feat[q];
  const float den = fmaxf(sqrtf(nn), 1e-12f);
#pragma unroll
  for (int q = 0; q < 16; ++q) feat[q] /= den;

  float eff[8];
#pragma unroll
  for (int k = 0; k < 8; ++k) {
    float s2 = 0.f;
#pragma unroll
    for (int q = 0; q < 16; ++q) { const float sv = sigs[k * 16 + q]; s2 += sv * sv; }
    const float sden = fmaxf(sqrtf(s2), 1e-12f);
    float dot = 0.f;
#pragma unroll
    for (int q = 0; q < 16; ++q) dot += feat[q] * (sigs[k * 16 + q] / sden);
    eff[k] = pe[k] * ((dot + 1.0f) / 2.0f);
  }

  float z = cl_b2[0];
#pragma unroll
  for (int cc = 0; cc < 16; ++cc) { float v = S[40 + cc] + cl_b1[cc]; v = v > 0.f ? v : 0.f; z += v * cl_w2[cc]; }
  const float clar = 1.0f / (1.0f + expf(-z));

  if (lane == 0) {
#pragma unroll
    for (int k = 0; k < 8; ++k) eff_o[tok * 8 + k] = eff[k];
    shc[wid] = clar;
#pragma unroll
    for (int k = 0; k < 8; ++k) shP[wid][k] = pe[k];
  }
  __syncthreads();
  if (t == 0) {
    pclar[blockIdx.x] = shc[0] + shc[1] + shc[2] + shc[3];
#pragma unroll
    for (int k = 0; k < 8; ++k)
      pP[blockIdx.x * 8 + k] = shP[0][k] + shP[1][k] + shP[2][k] + shP[3][k];
  }
}

// ---------------------------------------------------------------------------
__global__ void zero_kernel(int* __restrict__ gcount) {
  if (threadIdx.x < 8) gcount[threadIdx.x] = 0;
}

// k + top-k mask + weight normalization + active counts + per-expert lists
__global__ __launch_bounds__(256) void weights_kernel(
    const float* __restrict__ eff_i, const float* __restrict__ pclar,
    float* __restrict__ wout, int* __restrict__ f_part,
    int* __restrict__ gcount, int* __restrict__ lst)
{
  __shared__ float red[256];
  __shared__ int cnt[8];
  __shared__ int ksh;
  const int tid = threadIdx.x;
  float s = 0.f;
  for (int i = tid; i < 2048; i += 256) s += pclar[i];
  red[tid] = s; __syncthreads();
  for (int off = 128; off > 0; off >>= 1) { if (tid < off) red[tid] += red[tid + off]; __syncthreads(); }
  if (tid == 0) {
    const float mean_na = 8.0f - 6.0f * (red[0] / 8192.0f);
    int k = (int)floorf(mean_na + 0.5f);
    ksh = k < 2 ? 2 : (k > 8 ? 8 : k);
  }
  if (tid < 8) cnt[tid] = 0;
  __syncthreads();
  const int k = ksh;
  const int t = blockIdx.x * 256 + tid;
  const f32x4* ep = (const f32x4*)(eff_i + t * 8);
  const f32x4 ea = ep[0], eb = ep[1];
  const float ef[8] = {ea[0], ea[1], ea[2], ea[3], eb[0], eb[1], eb[2], eb[3]};
  float w[8]; float wsum = 0.f; int act[8];
#pragma unroll
  for (int e2 = 0; e2 < 8; ++e2) {
    int r = 0;
#pragma unroll
    for (int j = 0; j < 8; ++j) r += (int)((ef[j] > ef[e2]) || ((j < e2) && (ef[j] == ef[e2])));
    const float we = (r < k) ? ef[e2] : 0.f;
    w[e2] = we; wsum += we; act[e2] = we > 0.f ? 1 : 0;
  }
  const float dn = wsum + 1e-8f;
#pragma unroll
  for (int e2 = 0; e2 < 8; ++e2) wout[t * 8 + e2] = w[e2] / dn;
#pragma unroll
  for (int e2 = 0; e2 < 8; ++e2)
    if (act[e2]) {
      atomicAdd(&cnt[e2], 1);
      const int p = atomicAdd(&gcount[e2], 1);
      lst[e2 * N_TOK + p] = t;
    }
  __syncthreads();
  if (tid < 8) f_part[blockIdx.x * 8 + tid] = cnt[tid];
}

// pad each expert list to a multiple of 128 with a duplicate token
__global__ __launch_bounds__(256) void pad_kernel(
    const int* __restrict__ gcount, int* __restrict__ gpad, int* __restrict__ lst)
{
  const int tid = threadIdx.x;
  for (int e2 = 0; e2 < 8; ++e2) {
    const int a = gcount[e2];
    const int pc = (a + 127) & ~127;
    if (tid == 0) gpad[e2] = pc;
    if (a > 0) {
      const int last = lst[e2 * N_TOK + a - 1];
      for (int i = a + tid; i < pc; i += 256) lst[e2 * N_TOK + i] = last;
    }
  }
}

__global__ __launch_bounds__(256) void lb_kernel(
    const float* __restrict__ pP, const int* __restrict__ f_part, float* __restrict__ lbout)
{
  __shared__ float red[256];
  __shared__ float Ps[8], Fs[8];
  const int tid = threadIdx.x;
  for (int e2 = 0; e2 < 8; ++e2) {
    float s = 0.f;
    for (int i = tid; i < 2048; i += 256) s += pP[i * 8 + e2];
    red[tid] = s; __syncthreads();
    for (int off = 128; off > 0; off >>= 1) { if (tid < off) red[tid] += red[tid + off]; __syncthreads(); }
    if (tid == 0) Ps[e2] = red[0];
    __syncthreads();
    red[tid] = (tid < 32) ? (float)f_part[tid * 8 + e2] : 0.f;
    __syncthreads();
    for (int off = 128; off > 0; off >>= 1) { if (tid < off) red[tid] += red[tid + off]; __syncthreads(); }
    if (tid == 0) Fs[e2] = red[0];
    __syncthreads();
  }
  if (tid == 0) {
    float lb = 0.f;
    for (int e2 = 0; e2 < 8; ++e2) lb += (Fs[e2] / 8192.0f) * (Ps[e2] / 8192.0f);
    lbout[0] = 0.01f * 8.0f * lb;
  }
}

__global__ __launch_bounds__(256) void yinit_kernel(
    const float* __restrict__ w, const float* __restrict__ b2, float* __restrict__ y)
{
  const int idx = blockIdx.x * 256 + threadIdx.x;   // over N*O/4
  const int n = idx >> 8, o4 = idx & 255;
  const f32x4* bv = (const f32x4*)b2;
  f32x4 a = f32x4{0.f, 0.f, 0.f, 0.f};
  const float* wr = w + n * 8;
#pragma unroll
  for (int e2 = 0; e2 < 8; ++e2) a += wr[e2] * bv[e2 * 256 + o4];
  ((f32x4*)y)[idx] = a;
}

// per-expert [R,C] f32 -> [C,R] fp16
__global__ __launch_bounds__(256) void transpose_kernel(
    const float* __restrict__ in, unsigned short* __restrict__ out, int R, int C)
{
  __shared__ __align__(16) unsigned short tb[64][72];
  const float* ip = in + (size_t)blockIdx.z * R * C;
  unsigned short* op = out + (size_t)blockIdx.z * R * C;
  const int r0 = blockIdx.y * 64, c0 = blockIdx.x * 64;
  const int tr = threadIdx.x >> 4, tc4 = (threadIdx.x & 15) * 4;
#pragma unroll
  for (int i = 0; i < 4; ++i) {
    const int rr = tr + i * 16;
    const f32x4 v = *(const f32x4*)(ip + (size_t)(r0 + rr) * C + c0 + tc4);
#pragma unroll
    for (int j = 0; j < 4; ++j) tb[tc4 + j][rr] = f2h(v[j]);
  }
  __syncthreads();
  const int oc = threadIdx.x >> 3, or8 = (threadIdx.x & 7) * 8;
#pragma unroll
  for (int i = 0; i < 2; ++i) {
    const int c = oc + i * 32;
    const us8 v = *(const us8*)&tb[c][or8];
    *(us8*)(op + (size_t)(c0 + c) * R + r0 + or8) = v;
  }
}

// ---------------------------------------------------------------------------
extern "C" void kernel_launch(void* const* d_in, const int* in_sizes, int n_in,
                              void* d_out, int out_size, void* d_ws, size_t ws_size,
                              hipStream_t stream)
{
  const float* x      = (const float*)d_in[0];
  const float* gate_w = (const float*)d_in[1];
  const float* gate_b = (const float*)d_in[2];
  const float* ph_w1  = (const float*)d_in[3];
  const float* ph_b1  = (const float*)d_in[4];
  const float* ph_w2  = (const float*)d_in[5];
  const float* ph_b2  = (const float*)d_in[6];
  const float* cl_w1  = (const float*)d_in[7];
  const float* cl_b1  = (const float*)d_in[8];
  const float* cl_w2  = (const float*)d_in[9];
  const float* cl_b2  = (const float*)d_in[10];
  const float* sigs   = (const float*)d_in[11];
  const float* e_w1   = (const float*)d_in[12];
  const float* e_b1   = (const float*)d_in[13];
  const float* e_w2   = (const float*)d_in[14];
  const float* e_b2   = (const float*)d_in[15];
  float* y = (float*)d_out;
  char* ws = (char*)d_ws;

  float* eff    = (float*)(ws + 0);          // 8192*8*4
  float* wts    = (float*)(ws + 262144);     // 8192*8*4
  float* pclar  = (float*)(ws + 524288);     // 2048*4
  float* pP     = (float*)(ws + 532480);     // 2048*8*4
  int*   f_part = (int*)(ws + 598016);       // 32*8*4
  int*   gcount = (int*)(ws + 599040);       // 8*4
  int*   gpad   = (int*)(ws + 599072);       // 8*4
  int*   lst    = (int*)(ws + 655360);       // 8*8192*4
  unsigned short* xh  = (unsigned short*)(ws + 1048576);     // [N][D] fp16
  unsigned short* W1T = (unsigned short*)(ws + 17825792u);   // [E][H][D] fp16
  unsigned short* W2T = (unsigned short*)(ws + 51380224u);   // [E][O][H] fp16
  unsigned short* Hh  = (unsigned short*)(ws + 84934656u);   // [slots][H] fp16

  transpose_kernel<<<dim3(32, 16, 8), 256, 0, stream>>>(e_w1, W1T, 1024, 2048);
  transpose_kernel<<<dim3(16, 32, 8), 256, 0, stream>>>(e_w2, W2T, 2048, 1024);
  gating_kernel<<<2048, 256, 0, stream>>>(x, gate_w, gate_b, ph_w1, ph_b1, ph_w2, ph_b2,
                                          cl_w1, cl_b1, cl_w2, cl_b2, sigs,
                                          xh, eff, pclar, pP);
  zero_kernel<<<1, 64, 0, stream>>>(gcount);
  weights_kernel<<<32, 256, 0, stream>>>(eff, pclar, wts, f_part, gcount, lst);
  pad_kernel<<<1, 256, 0, stream>>>(gcount, gpad, lst);
  lb_kernel<<<1, 256, 0, stream>>>(pP, f_part, y + (size_t)N_TOK * ODIM);
  yinit_kernel<<<8192, 256, 0, stream>>>(wts, e_b2, y);

  for (int e2 = 0; e2 < 8; ++e2) {
    gemm_kernel<1><<<dim3(16, 64), 256, 0, stream>>>(
        xh, W1T + (size_t)e2 * HDIM * DIM, HDIM, DIM,
        e_b1 + e2 * HDIM, Hh, nullptr, e2, nullptr,
        lst + (size_t)e2 * N_TOK, gcount, gpad);
    gemm_kernel<2><<<dim3(8, 64), 256, 0, stream>>>(
        Hh, W2T + (size_t)e2 * ODIM * HDIM, ODIM, HDIM,
        nullptr, nullptr, wts, e2, y,
        lst + (size_t)e2 * N_TOK, gcount, gpad);
  }
}